// Round 5
// baseline (2123.243 us; speedup 1.0000x reference)
//
#include <hip/hip_runtime.h>

#define HID   24
#define T_LEN 4096
#define BATCH 1024
#define KC    4                  // timesteps per chunk/tick
#define NC    (T_LEN / KC)       // 1024 active ticks per layer
#define CTOT  (NC + 2)           // 1026 ticks (3-layer skew)
#define NBATCH 32                // batches per block (= MFMA N)
#define TPB   192                // 3 waves: wave l == layer l

typedef __attribute__((ext_vector_type(8)))  short bf16x8;
typedef __attribute__((ext_vector_type(16))) float f32x16;
typedef __attribute__((ext_vector_type(4)))  int   int4v;
typedef __attribute__((ext_vector_type(2)))  int   int2v;

#define MFMA(A_, B_, C_) __builtin_amdgcn_mfma_f32_32x32x16_bf16( \
    __builtin_bit_cast(bf16x8, (A_)), __builtin_bit_cast(bf16x8, (B_)), (C_), 0, 0, 0)

// pack two floats' truncated-bf16 into one dword: low16 = bf16(a), high16 = bf16(b)
__device__ __forceinline__ int pack2(float a, float b) {
    return (int)((__float_as_uint(a) >> 16) | (__float_as_uint(b) & 0xffff0000u));
}
// f32 value of truncated-bf16(a)
__device__ __forceinline__ float hif(float a) {
    return __uint_as_float(__float_as_uint(a) & 0xffff0000u);
}

__global__ __launch_bounds__(TPB, 1) void rnn_mfma_kernel(
    const float* __restrict__ x, const float* __restrict__ h_in,
    const float* __restrict__ Wih0, const float* __restrict__ bih0,
    const float* __restrict__ Whh0, const float* __restrict__ bhh0,
    const float* __restrict__ Wih1, const float* __restrict__ bih1,
    const float* __restrict__ Whh1, const float* __restrict__ bhh1,
    const float* __restrict__ Wih2, const float* __restrict__ bih2,
    const float* __restrict__ Whh2, const float* __restrict__ bhh2,
    const float* __restrict__ W1,   const float* __restrict__ b1,
    const float* __restrict__ W2,   const float* __restrict__ b2,
    float* __restrict__ out)         // [1024 y] ++ [3*1024*24 h_final]
{
    // published inter-layer activations: packed bf16 pairs, [par][srclayer][step][batch][pair]
    __shared__ __align__(16) int pubHi[2 * 2 * KC * NBATCH * 12];
    __shared__ __align__(16) int pubLo[2 * 2 * KC * NBATCH * 12];
    __shared__ float h2f[NBATCH][HID];

    const int tid  = threadIdx.x;
    const int l    = tid >> 6;       // wave == layer
    const int lane = tid & 63;
    const int h    = lane >> 5;      // half (K-split of MFMA operands)
    const int n    = lane & 31;      // batch-in-block == MFMA column
    const int b    = blockIdx.x * NBATCH + n;

    const float* Wih  = (l == 1) ? Wih1 : Wih2;              // unused for l==0
    const float* Whh  = (l == 0) ? Whh0 : (l == 1) ? Whh1 : Whh2;
    const float* bihp = (l == 0) ? bih0 : (l == 1) ? bih1 : bih2;
    const float* bhhp = (l == 0) ? bhh0 : (l == 1) ? bhh1 : bhh2;

    const int row  = n;                              // A-fragment row = output unit
    const int rowc = (row < HID) ? row : HID - 1;    // safe address for pad rows

    // ---- stationary weight A-fragments (hi/lo split), K-stack = [inp24 ; own24] ----
    int4v wt0h, wt0l, wt1h, wt1l, wt2h, wt2l;
#define BUILDW(TB, DH, DL) do {                                                      \
        float wf[8], wl[8];                                                          \
        _Pragma("unroll")                                                            \
        for (int e = 0; e < 8; ++e) {                                                \
            const int kk = (TB) + h * 8 + e;                                         \
            float w_ = 0.f;                                                          \
            if (row < HID) {                                                         \
                if (kk < HID)                                                        \
                    w_ = (l == 0) ? ((kk == 0) ? Wih0[rowc] : 0.f)                   \
                                  : Wih[rowc * HID + kk];                            \
                else                                                                 \
                    w_ = Whh[rowc * HID + kk - HID];                                 \
            }                                                                        \
            wf[e] = w_; wl[e] = w_ - hif(w_);                                        \
        }                                                                            \
        DH = (int4v){ pack2(wf[0], wf[1]), pack2(wf[2], wf[3]),                      \
                      pack2(wf[4], wf[5]), pack2(wf[6], wf[7]) };                    \
        DL = (int4v){ pack2(wl[0], wl[1]), pack2(wl[2], wl[3]),                      \
                      pack2(wl[4], wl[5]), pack2(wl[6], wl[7]) };                    \
    } while (0)
    BUILDW(0,  wt0h, wt0l);
    BUILDW(16, wt1h, wt1l);
    BUILDW(32, wt2h, wt2l);
#undef BUILDW

    // ---- bias folded into the first MFMA's C-in; acc rows r<12 are real units ----
    f32x16 biasC = {};
    f32x16 Zc    = {};
    #pragma unroll
    for (int r = 0; r < 12; ++r) {
        const int u = (r & 3) + 8 * (r >> 2) + 4 * h;
        biasC[r] = bihp[u] + bhhp[u];
    }

    // ---- initial state as packed pairs (pk q: local pair regs) + f32 copy ----
    const float* hb = h_in + (size_t)(l * BATCH + b) * HID;
    int pk0h, pk1h, pk2h, pk3h, pk4h, pk5h;
    int pk0l, pk1l, pk2l, pk3l, pk4l, pk5l;
#define INITPK(GP0, PH, PL) do {                                                     \
        const int gp = (GP0) + 2 * h;                                                \
        const float a_ = hb[2 * gp], c_ = hb[2 * gp + 1];                            \
        PH = pack2(a_, c_);                                                          \
        PL = pack2(a_ - hif(a_), c_ - hif(c_));                                      \
    } while (0)
    INITPK(0, pk0h, pk0l); INITPK(1, pk1h, pk1l);
    INITPK(4, pk2h, pk2l); INITPK(5, pk3h, pk3l);
    INITPK(8, pk4h, pk4l); INITPK(9, pk5h, pk5l);
#undef INITPK

    float vsv[12];
    #pragma unroll
    for (int r = 0; r < 12; ++r) vsv[r] = hb[(r & 3) + 8 * (r >> 2) + 4 * h];

    float4 xq = make_float4(0.f, 0.f, 0.f, 0.f);
    if (l == 0) xq = *(const float4*)&x[(size_t)b * T_LEN];

#define LOADQ(D0H, D0L, D1H, D1L, S_) do {                                           \
        const int rb = (((rp * 2 + (l - 1)) * KC + (S_)) * NBATCH + n) * 12;         \
        D0H = *(const int4v*)&pubHi[rb + 4 * h];                                     \
        D0L = *(const int4v*)&pubLo[rb + 4 * h];                                     \
        D1H = *(const int4v*)&pubHi[rb + 8];                                         \
        D1L = *(const int4v*)&pubLo[rb + 8];                                         \
    } while (0)

// One timestep: T0 = inp k0-15 fragment (from LDS or x); Q1 = LDS part of T1 (inp k16-23).
// Own-state fragments built in-lane from pk regs + 12 half-swaps.
#define STEPCORE(T0H_, T0L_, Q1H_, Q1L_, S_) do {                                    \
        const int x0h = __shfl_xor(pk0h, 32), x1h = __shfl_xor(pk1h, 32);            \
        const int x2h = __shfl_xor(pk2h, 32), x3h = __shfl_xor(pk3h, 32);            \
        const int x4h = __shfl_xor(pk4h, 32), x5h = __shfl_xor(pk5h, 32);            \
        const int x0l = __shfl_xor(pk0l, 32), x1l = __shfl_xor(pk1l, 32);            \
        const int x2l = __shfl_xor(pk2l, 32), x3l = __shfl_xor(pk3l, 32);            \
        const int x4l = __shfl_xor(pk4l, 32), x5l = __shfl_xor(pk5l, 32);            \
        const int4v T1H = { h ? x0h : Q1H_.x, h ? x1h : Q1H_.y,                      \
                            h ? pk0h : Q1H_.z, h ? pk1h : Q1H_.w };                  \
        const int4v T1L = { h ? x0l : Q1L_.x, h ? x1l : Q1L_.y,                      \
                            h ? pk0l : Q1L_.z, h ? pk1l : Q1L_.w };                  \
        const int4v T2H = { h ? x4h : pk2h, h ? x5h : pk3h,                          \
                            h ? pk4h : x2h, h ? pk5h : x3h };                        \
        const int4v T2L = { h ? x4l : pk2l, h ? x5l : pk3l,                          \
                            h ? pk4l : x2l, h ? pk5l : x3l };                        \
        f32x16 Ac = MFMA(wt0h, T0H_, biasC);                                         \
        Ac = MFMA(wt0h, T0L_, Ac);                                                   \
        Ac = MFMA(wt0l, T0H_, Ac);                                                   \
        f32x16 Bc = MFMA(wt1h, T1H, Zc);                                             \
        Bc = MFMA(wt1h, T1L, Bc);                                                    \
        Bc = MFMA(wt1l, T1H, Bc);                                                    \
        Bc = MFMA(wt2h, T2H, Bc);                                                    \
        Bc = MFMA(wt2h, T2L, Bc);                                                    \
        Bc = MFMA(wt2l, T2H, Bc);                                                    \
        _Pragma("unroll")                                                            \
        for (int r = 0; r < 12; ++r) vsv[r] = fmaxf(Ac[r] + Bc[r], 0.f);             \
        pk0h = pack2(vsv[0], vsv[1]);                                                \
        pk0l = pack2(vsv[0] - hif(vsv[0]), vsv[1] - hif(vsv[1]));                    \
        pk1h = pack2(vsv[2], vsv[3]);                                                \
        pk1l = pack2(vsv[2] - hif(vsv[2]), vsv[3] - hif(vsv[3]));                    \
        pk2h = pack2(vsv[4], vsv[5]);                                                \
        pk2l = pack2(vsv[4] - hif(vsv[4]), vsv[5] - hif(vsv[5]));                    \
        pk3h = pack2(vsv[6], vsv[7]);                                                \
        pk3l = pack2(vsv[6] - hif(vsv[6]), vsv[7] - hif(vsv[7]));                    \
        pk4h = pack2(vsv[8], vsv[9]);                                                \
        pk4l = pack2(vsv[8] - hif(vsv[8]), vsv[9] - hif(vsv[9]));                    \
        pk5h = pack2(vsv[10], vsv[11]);                                              \
        pk5l = pack2(vsv[10] - hif(vsv[10]), vsv[11] - hif(vsv[11]));                \
        if (l < 2) {                                                                 \
            const int pb = (((wp * 2 + l) * KC + (S_)) * NBATCH + n) * 12;           \
            *(int2v*)&pubHi[pb + 2 * h]     = (int2v){pk0h, pk1h};                   \
            *(int2v*)&pubHi[pb + 4 + 2 * h] = (int2v){pk2h, pk3h};                   \
            *(int2v*)&pubHi[pb + 8 + 2 * h] = (int2v){pk4h, pk5h};                   \
            *(int2v*)&pubLo[pb + 2 * h]     = (int2v){pk0l, pk1l};                   \
            *(int2v*)&pubLo[pb + 4 + 2 * h] = (int2v){pk2l, pk3l};                   \
            *(int2v*)&pubLo[pb + 8 + 2 * h] = (int2v){pk4l, pk5l};                   \
        }                                                                            \
    } while (0)

    // ---- chunked, layer-skewed scan: tick c, layer l handles t in [(c-l)*KC, +KC) ----
    for (int c = 0; c < CTOT; ++c) {
        const int wp = c & 1, rp = wp ^ 1;
        if (c >= l && c < l + NC) {
            if (l == 0) {
                float4 xq_n = xq;
                if (c + 1 < NC)
                    xq_n = *(const float4*)&x[(size_t)b * T_LEN + (size_t)(c + 1) * KC];
                #pragma unroll
                for (int s = 0; s < KC; ++s) {
                    const float xv = (s == 0) ? xq.x : (s == 1) ? xq.y
                                   : (s == 2) ? xq.z : xq.w;
                    const float xl = xv - hif(xv);
                    const int4v T0H = { h ? 0 : (int)(__float_as_uint(xv) >> 16), 0, 0, 0 };
                    const int4v T0L = { h ? 0 : (int)(__float_as_uint(xl) >> 16), 0, 0, 0 };
                    const int4v Q1H = {0, 0, 0, 0}, Q1L = {0, 0, 0, 0};
                    STEPCORE(T0H, T0L, Q1H, Q1L, s);
                }
                xq = xq_n;
            } else {
                int4v a0h, a0l, a1h, a1l;
                LOADQ(a0h, a0l, a1h, a1l, 0);
                #pragma unroll
                for (int s = 0; s < KC; ++s) {
                    int4v b0h, b0l, b1h, b1l;
                    if (s + 1 < KC) LOADQ(b0h, b0l, b1h, b1l, s + 1);
                    STEPCORE(a0h, a0l, a1h, a1l, s);
                    if (s + 1 < KC) { a0h = b0h; a0l = b0l; a1h = b1h; a1l = b1l; }
                }
            }
        }
        __syncthreads();
    }
#undef STEPCORE
#undef LOADQ

    // ---- h_final ----
    #pragma unroll
    for (int r = 0; r < 12; ++r) {
        const int u = (r & 3) + 8 * (r >> 2) + 4 * h;
        out[BATCH + (size_t)(l * BATCH + b) * HID + u] = vsv[r];
    }

    // ---- MLP head on h2(T-1) ----
    if (l == 2) {
        #pragma unroll
        for (int r = 0; r < 12; ++r) {
            const int u = (r & 3) + 8 * (r >> 2) + 4 * h;
            h2f[n][u] = vsv[r];
        }
    }
    __syncthreads();
    if (tid < NBATCH) {
        float acc2 = b2[0];
        for (int j = 0; j < HID; ++j) {
            float a_ = b1[j];
            for (int k2 = 0; k2 < HID; ++k2)
                a_ = fmaf(W1[j * HID + k2], h2f[tid][k2], a_);
            acc2 = fmaf(W2[j], fmaxf(a_, 0.f), acc2);
        }
        out[blockIdx.x * NBATCH + tid] = fmaxf(acc2, 0.f);
    }
}

extern "C" void kernel_launch(void* const* d_in, const int* in_sizes, int n_in,
                              void* d_out, int out_size, void* d_ws, size_t ws_size,
                              hipStream_t stream) {
    const float* x    = (const float*)d_in[0];
    const float* h_in = (const float*)d_in[1];
    const float* Wih0 = (const float*)d_in[2];
    const float* bih0 = (const float*)d_in[3];
    const float* Whh0 = (const float*)d_in[4];
    const float* bhh0 = (const float*)d_in[5];
    const float* Wih1 = (const float*)d_in[6];
    const float* bih1 = (const float*)d_in[7];
    const float* Whh1 = (const float*)d_in[8];
    const float* bhh1 = (const float*)d_in[9];
    const float* Wih2 = (const float*)d_in[10];
    const float* bih2 = (const float*)d_in[11];
    const float* Whh2 = (const float*)d_in[12];
    const float* bhh2 = (const float*)d_in[13];
    const float* W1   = (const float*)d_in[14];
    const float* b1   = (const float*)d_in[15];
    const float* W2   = (const float*)d_in[16];
    const float* b2   = (const float*)d_in[17];
    float* out = (float*)d_out;

    dim3 grid(BATCH / NBATCH);   // 32 blocks
    dim3 block(TPB);             // 3 waves (wave == layer)
    hipLaunchKernelGGL(rnn_mfma_kernel, grid, block, 0, stream,
                       x, h_in, Wih0, bih0, Whh0, bhh0,
                       Wih1, bih1, Whh1, bhh1, Wih2, bih2, Whh2, bhh2,
                       W1, b1, W2, b2, out);
}

// Round 6
// 1122.283 us; speedup vs baseline: 1.8919x; 1.8919x over previous
//
#include <hip/hip_runtime.h>

#define HID   24
#define T_LEN 4096
#define BATCH 1024
#define NB    2                  // batches per wave (one per 32-lane half)
#define K     8                  // timesteps per chunk (pipeline skew per layer)
#define NC    (T_LEN / K)        // 512 active chunks per layer
#define CTOT  (NC + 2)           // 514 ticks total (3-layer skew)
#define XC    512                // x staging chunk (elements)
#define TPB   192                // 3 full waves: wave w == layer w

typedef __attribute__((ext_vector_type(2))) _Float16 h2v;
typedef __attribute__((ext_vector_type(4))) int      int4v;

__device__ __forceinline__ float dot2f(int p, int w, float acc) {
#if __has_builtin(__builtin_amdgcn_fdot2)
    return __builtin_amdgcn_fdot2(__builtin_bit_cast(h2v, p),
                                  __builtin_bit_cast(h2v, w), acc, false);
#else
    h2v a = __builtin_bit_cast(h2v, p), b = __builtin_bit_cast(h2v, w);
    acc = fmaf((float)a.x, (float)b.x, acc);
    return fmaf((float)a.y, (float)b.y, acc);
#endif
}

__device__ __forceinline__ float dot4(const float4 a, const float4 b, float acc) {
    acc = fmaf(a.x, b.x, acc);
    acc = fmaf(a.y, b.y, acc);
    acc = fmaf(a.z, b.z, acc);
    acc = fmaf(a.w, b.w, acc);
    return acc;
}

__global__ __launch_bounds__(TPB, 1) void rnn_scan_kernel(
    const float* __restrict__ x,     // [B, T]
    const float* __restrict__ h_in,  // [3, B, 24]
    const float* __restrict__ Wih0, const float* __restrict__ bih0,
    const float* __restrict__ Whh0, const float* __restrict__ bhh0,
    const float* __restrict__ Wih1, const float* __restrict__ bih1,
    const float* __restrict__ Whh1, const float* __restrict__ bhh1,
    const float* __restrict__ Wih2, const float* __restrict__ bih2,
    const float* __restrict__ Whh2, const float* __restrict__ bhh2,
    const float* __restrict__ W1,   const float* __restrict__ b1,
    const float* __restrict__ W2,   const float* __restrict__ b2,
    float* __restrict__ out)         // [1024 (y)] ++ [3*1024*24 (h_final)]
{
    // hbuf: packed-f16 state, [par][bl][layer][step][24]; row = 48B (16B-aligned)
    __shared__ __align__(16) _Float16 hbuf[2][NB][3][K][HID];
    __shared__ __align__(16) float xs[NB][XC];
    __shared__ float h2f[NB][HID];
    __shared__ float mbuf[NB][HID];

    const int tid  = threadIdx.x;
    const int l    = tid >> 6;        // wave id == layer
    const int lane = tid & 63;
    const int bl   = lane >> 5;       // batch half
    const int jj   = lane & 31;
    const bool act = (jj < HID);
    const int j    = act ? jj : 0;    // clamped for safe addressing
    const int bg   = blockIdx.x * NB + bl;

    // ---- weights: split f16 (hi+lo) packed pairs, in named int4v registers ----
    // wiH*/wiL*: input-from-below row (layers 1,2); whH*/whL*: own-h row
    int4v wiH0, wiH1, wiH2, wiL0, wiL1, wiL2;
    int4v whH0, whH1, whH2, whL0, whL1, whL2;
    float wx0 = 0.f, bias;

#define MK4(ROW, K0, DH, DL) do {                                                   \
        int h_[4], l_[4];                                                           \
        _Pragma("unroll")                                                           \
        for (int e = 0; e < 4; ++e) {                                               \
            const float w0 = (ROW)[(K0) + 2 * e], w1 = (ROW)[(K0) + 2 * e + 1];     \
            const _Float16 ph0 = (_Float16)w0, ph1 = (_Float16)w1;                  \
            const _Float16 pl0 = (_Float16)(w0 - (float)ph0);                       \
            const _Float16 pl1 = (_Float16)(w1 - (float)ph1);                       \
            h_[e] = ((int)__builtin_bit_cast(unsigned short, ph1) << 16) |          \
                    (int)__builtin_bit_cast(unsigned short, ph0);                   \
            l_[e] = ((int)__builtin_bit_cast(unsigned short, pl1) << 16) |          \
                    (int)__builtin_bit_cast(unsigned short, pl0);                   \
        }                                                                           \
        DH = (int4v){h_[0], h_[1], h_[2], h_[3]};                                   \
        DL = (int4v){l_[0], l_[1], l_[2], l_[3]};                                   \
    } while (0)

    {
        const float* hhrow = ((l == 0) ? Whh0 : (l == 1) ? Whh1 : Whh2) + j * HID;
        MK4(hhrow, 0, whH0, whL0);
        MK4(hhrow, 8, whH1, whL1);
        MK4(hhrow, 16, whH2, whL2);
        if (l == 0) {
            wx0 = Wih0[j];
            bias = bih0[j] + bhh0[j];
            wiH0 = wiH1 = wiH2 = (int4v){0, 0, 0, 0};
            wiL0 = wiL1 = wiL2 = (int4v){0, 0, 0, 0};
        } else {
            const float* ihrow = ((l == 1) ? Wih1 : Wih2) + j * HID;
            MK4(ihrow, 0, wiH0, wiL0);
            MK4(ihrow, 8, wiH1, wiL1);
            MK4(ihrow, 16, wiH2, wiL2);
            bias = (l == 1) ? (bih1[j] + bhh1[j]) : (bih2[j] + bhh2[j]);
        }
    }
#undef MK4

    float cur = act ? h_in[(l * BATCH + bg) * HID + j] : 0.f;

    // seed both parities' [l][K-1] rows with the initial state
    if (act) {
        hbuf[0][bl][l][K - 1][j] = (_Float16)cur;
        hbuf[1][bl][l][K - 1][j] = (_Float16)cur;
    }
    // stage first x region
    for (int idx = tid; idx < NB * XC / 4; idx += TPB) {
        const int bb = idx / (XC / 4), o = idx % (XC / 4);
        ((float4*)&xs[bb][0])[o] =
            ((const float4*)(x + (size_t)(blockIdx.x * NB + bb) * T_LEN))[o];
    }
    __syncthreads();

// 24 packed dots (12 hi + 12 lo) of vector V against weight row (H,L) into a0..a3
#define DOTBLK(V0_, V1_, V2_, H0_, H1_, H2_, L0_, L1_, L2_)                         \
    a0 = dot2f(V0_.x, H0_.x, a0); a1 = dot2f(V0_.y, H0_.y, a1);                     \
    a2 = dot2f(V0_.z, H0_.z, a2); a3 = dot2f(V0_.w, H0_.w, a3);                     \
    a0 = dot2f(V1_.x, H1_.x, a0); a1 = dot2f(V1_.y, H1_.y, a1);                     \
    a2 = dot2f(V1_.z, H1_.z, a2); a3 = dot2f(V1_.w, H1_.w, a3);                     \
    a0 = dot2f(V2_.x, H2_.x, a0); a1 = dot2f(V2_.y, H2_.y, a1);                     \
    a2 = dot2f(V2_.z, H2_.z, a2); a3 = dot2f(V2_.w, H2_.w, a3);                     \
    a0 = dot2f(V0_.x, L0_.x, a0); a1 = dot2f(V0_.y, L0_.y, a1);                     \
    a2 = dot2f(V0_.z, L0_.z, a2); a3 = dot2f(V0_.w, L0_.w, a3);                     \
    a0 = dot2f(V1_.x, L1_.x, a0); a1 = dot2f(V1_.y, L1_.y, a1);                     \
    a2 = dot2f(V1_.z, L1_.z, a2); a3 = dot2f(V1_.w, L1_.w, a3);                     \
    a0 = dot2f(V2_.x, L2_.x, a0); a1 = dot2f(V2_.y, L2_.y, a1);                     \
    a2 = dot2f(V2_.z, L2_.z, a2); a3 = dot2f(V2_.w, L2_.w, a3);

    // ---- chunked, layer-skewed scan: tick c, layer l handles t in [(c-l)*K, +K) ----
    for (int c = 0; c < CTOT; ++c) {
        const int wp = c & 1, rp = wp ^ 1;
        if (c >= l && c < l + NC) {
            if (l == 0) {
                const int xoff = (c * K) & (XC - 1);
                const float4 xq0 = *(const float4*)&xs[bl][xoff];
                const float4 xq1 = *(const float4*)&xs[bl][xoff + 4];
                #pragma unroll
                for (int s = 0; s < K; ++s) {
                    const int4v* own = (s == 0)
                        ? (const int4v*)&hbuf[rp][bl][0][K - 1][0]
                        : (const int4v*)&hbuf[wp][bl][0][s - 1][0];
                    const int4v o0 = own[0], o1 = own[1], o2 = own[2];
                    const float xv = (s == 0) ? xq0.x : (s == 1) ? xq0.y
                                   : (s == 2) ? xq0.z : (s == 3) ? xq0.w
                                   : (s == 4) ? xq1.x : (s == 5) ? xq1.y
                                   : (s == 6) ? xq1.z : xq1.w;
                    float a0 = wx0 * xv, a1 = 0.f, a2 = 0.f, a3 = 0.f;
                    DOTBLK(o0, o1, o2, whH0, whH1, whH2, whL0, whL1, whL2);
                    cur = fmaxf(bias + ((a0 + a1) + (a2 + a3)), 0.f);
                    if (act) hbuf[wp][bl][0][s][j] = (_Float16)cur;
                }
            } else {
                const int4v* ir0 = (const int4v*)&hbuf[rp][bl][l - 1][0][0];
                int4v iA0 = ir0[0], iA1 = ir0[1], iA2 = ir0[2];
                #pragma unroll
                for (int s = 0; s < K; ++s) {
                    int4v iB0, iB1, iB2;
                    if (s + 1 < K) {
                        const int4v* nr = (const int4v*)&hbuf[rp][bl][l - 1][s + 1][0];
                        iB0 = nr[0]; iB1 = nr[1]; iB2 = nr[2];
                    }
                    const int4v* own = (s == 0)
                        ? (const int4v*)&hbuf[rp][bl][l][K - 1][0]
                        : (const int4v*)&hbuf[wp][bl][l][s - 1][0];
                    const int4v o0 = own[0], o1 = own[1], o2 = own[2];
                    float a0 = 0.f, a1 = 0.f, a2 = 0.f, a3 = 0.f;
                    DOTBLK(iA0, iA1, iA2, wiH0, wiH1, wiH2, wiL0, wiL1, wiL2);
                    DOTBLK(o0, o1, o2, whH0, whH1, whH2, whL0, whL1, whL2);
                    cur = fmaxf(bias + ((a0 + a1) + (a2 + a3)), 0.f);
                    if (act) hbuf[wp][bl][l][s][j] = (_Float16)cur;
                    if (s + 1 < K) { iA0 = iB0; iA1 = iB1; iA2 = iB2; }
                }
            }
        }
        __syncthreads();
        // stage next x region when the next chunk crosses an XC boundary
        const int cn = c + 1;
        if (cn < NC && ((cn * K) & (XC - 1)) == 0) {
            for (int idx = tid; idx < NB * XC / 4; idx += TPB) {
                const int bb = idx / (XC / 4), o = idx % (XC / 4);
                ((float4*)&xs[bb][0])[o] =
                    ((const float4*)(x + (size_t)(blockIdx.x * NB + bb) * T_LEN + cn * K))[o];
            }
            __syncthreads();
        }
    }
#undef DOTBLK

    // ---- h_final from registers (f32 running value) ----
    if (act) out[BATCH + (l * BATCH + bg) * HID + j] = cur;

    // ---- MLP head on h2(T-1) ----
    if (l == 2 && act) h2f[bl][j] = cur;
    __syncthreads();
    if (l == 2 && act) {
        const float4* w1r = (const float4*)(W1 + j * HID);
        const float4* hv  = (const float4*)&h2f[bl][0];
        float a = b1[j];
        a = dot4(w1r[0], hv[0], a); a = dot4(w1r[1], hv[1], a);
        a = dot4(w1r[2], hv[2], a); a = dot4(w1r[3], hv[3], a);
        a = dot4(w1r[4], hv[4], a); a = dot4(w1r[5], hv[5], a);
        mbuf[bl][j] = fmaxf(a, 0.f);
    }
    __syncthreads();
    if (l == 2 && jj == 0) {
        float a = b2[0];
        #pragma unroll
        for (int k = 0; k < HID; ++k) a = fmaf(W2[k], mbuf[bl][k], a);
        out[bg] = fmaxf(a, 0.f);
    }
}

extern "C" void kernel_launch(void* const* d_in, const int* in_sizes, int n_in,
                              void* d_out, int out_size, void* d_ws, size_t ws_size,
                              hipStream_t stream) {
    const float* x    = (const float*)d_in[0];
    const float* h_in = (const float*)d_in[1];
    const float* Wih0 = (const float*)d_in[2];
    const float* bih0 = (const float*)d_in[3];
    const float* Whh0 = (const float*)d_in[4];
    const float* bhh0 = (const float*)d_in[5];
    const float* Wih1 = (const float*)d_in[6];
    const float* bih1 = (const float*)d_in[7];
    const float* Whh1 = (const float*)d_in[8];
    const float* bhh1 = (const float*)d_in[9];
    const float* Wih2 = (const float*)d_in[10];
    const float* bih2 = (const float*)d_in[11];
    const float* Whh2 = (const float*)d_in[12];
    const float* bhh2 = (const float*)d_in[13];
    const float* W1   = (const float*)d_in[14];
    const float* b1   = (const float*)d_in[15];
    const float* W2   = (const float*)d_in[16];
    const float* b2   = (const float*)d_in[17];
    float* out = (float*)d_out;

    dim3 grid(BATCH / NB);   // 512 blocks -> 2 blocks/CU
    dim3 block(TPB);         // 3 full waves (wave == layer)
    hipLaunchKernelGGL(rnn_scan_kernel, grid, block, 0, stream,
                       x, h_in, Wih0, bih0, Whh0, bhh0,
                       Wih1, bih1, Whh1, bhh1, Wih2, bih2, Whh2, bhh2,
                       W1, b1, W2, b2, out);
}

// Round 7
// 699.493 us; speedup vs baseline: 3.0354x; 1.6044x over previous
//
#include <hip/hip_runtime.h>

#define HID   24
#define T_LEN 4096
#define BATCH 1024
#define NB    2                  // batches per wave (one per 32-lane half)
#define K     16                 // timesteps per chunk (pipeline skew per layer)
#define NC    (T_LEN / K)        // 256 active chunks per layer
#define CTOT  (NC + 2)           // 258 ticks total (3-layer skew)
#define TPB   192                // 3 full waves: wave w == layer w

typedef __attribute__((ext_vector_type(2))) _Float16 h2v;
typedef __attribute__((ext_vector_type(4))) int      int4v;

__device__ __forceinline__ float dot2f(int p, int w, float acc) {
#if __has_builtin(__builtin_amdgcn_fdot2)
    return __builtin_amdgcn_fdot2(__builtin_bit_cast(h2v, p),
                                  __builtin_bit_cast(h2v, w), acc, false);
#else
    h2v a = __builtin_bit_cast(h2v, p), b = __builtin_bit_cast(h2v, w);
    acc = fmaf((float)a.x, (float)b.x, acc);
    return fmaf((float)a.y, (float)b.y, acc);
#endif
}

__device__ __forceinline__ float dot4(const float4 a, const float4 b, float acc) {
    acc = fmaf(a.x, b.x, acc);
    acc = fmaf(a.y, b.y, acc);
    acc = fmaf(a.z, b.z, acc);
    acc = fmaf(a.w, b.w, acc);
    return acc;
}

// pack two f32 -> packed f16 pair dword
#define PKF(A_, B_)                                                                 \
    (((int)__builtin_bit_cast(unsigned short, (_Float16)(B_)) << 16) |              \
     (int)__builtin_bit_cast(unsigned short, (_Float16)(A_)))

__global__ __launch_bounds__(TPB, 1) void rnn_scan_kernel(
    const float* __restrict__ x,     // [B, T]
    const float* __restrict__ h_in,  // [3, B, 24]
    const float* __restrict__ Wih0, const float* __restrict__ bih0,
    const float* __restrict__ Whh0, const float* __restrict__ bhh0,
    const float* __restrict__ Wih1, const float* __restrict__ bih1,
    const float* __restrict__ Whh1, const float* __restrict__ bhh1,
    const float* __restrict__ Wih2, const float* __restrict__ bih2,
    const float* __restrict__ Whh2, const float* __restrict__ bhh2,
    const float* __restrict__ W1,   const float* __restrict__ b1,
    const float* __restrict__ W2,   const float* __restrict__ b2,
    float* __restrict__ out)         // [1024 (y)] ++ [3*1024*24 (h_final)]
{
    // packed-f16 state rows: [par][bl][layer][step][24], row = 48B (16B-aligned)
    __shared__ __align__(16) _Float16 hbuf[2][NB][3][K][HID];
    __shared__ float h2f[NB][HID];
    __shared__ float mbuf[NB][HID];

    const int tid  = threadIdx.x;
    const int l    = tid >> 6;        // wave id == layer
    const int lane = tid & 63;
    const int bl   = lane >> 5;       // batch half
    const int jj   = lane & 31;
    const bool act = (jj < HID);
    const int j    = act ? jj : 0;    // clamped for safe addressing
    const int bg   = blockIdx.x * NB + bl;

    // ---- weights: pure packed-f16, in named int4v registers ----
    int4v whA, whB, whC;              // own-h row (24 vals = 12 dwords)
    int4v wiA, wiB, wiC;              // input-from-below row (layers 1,2)
    float wx0 = 0.f, bias;

#define MK3(ROW, DA, DB, DC) do {                                                   \
        DA = (int4v){PKF((ROW)[0], (ROW)[1]),  PKF((ROW)[2], (ROW)[3]),             \
                     PKF((ROW)[4], (ROW)[5]),  PKF((ROW)[6], (ROW)[7])};            \
        DB = (int4v){PKF((ROW)[8], (ROW)[9]),  PKF((ROW)[10], (ROW)[11]),           \
                     PKF((ROW)[12], (ROW)[13]), PKF((ROW)[14], (ROW)[15])};         \
        DC = (int4v){PKF((ROW)[16], (ROW)[17]), PKF((ROW)[18], (ROW)[19]),          \
                     PKF((ROW)[20], (ROW)[21]), PKF((ROW)[22], (ROW)[23])};         \
    } while (0)

    {
        const float* hhrow = ((l == 0) ? Whh0 : (l == 1) ? Whh1 : Whh2) + j * HID;
        MK3(hhrow, whA, whB, whC);
        if (l == 0) {
            wx0 = Wih0[j];
            bias = bih0[j] + bhh0[j];
            wiA = wiB = wiC = (int4v){0, 0, 0, 0};
        } else {
            const float* ihrow = ((l == 1) ? Wih1 : Wih2) + j * HID;
            MK3(ihrow, wiA, wiB, wiC);
            bias = (l == 1) ? (bih1[j] + bhh1[j]) : (bih2[j] + bhh2[j]);
        }
    }
#undef MK3

    float cur = act ? h_in[(l * BATCH + bg) * HID + j] : 0.f;

    // seed both parities' [l][K-1] rows with the initial state
    if (act) {
        hbuf[0][bl][l][K - 1][j] = (_Float16)cur;
        hbuf[1][bl][l][K - 1][j] = (_Float16)cur;
    }

    // ---- x in registers (layer-0 wave only): current + prefetch quads ----
    float4 xq0, xq1, xq2, xq3;
    xq0 = xq1 = xq2 = xq3 = make_float4(0.f, 0.f, 0.f, 0.f);
    const float4* xrow = (const float4*)(x + (size_t)bg * T_LEN);
    if (l == 0) { xq0 = xrow[0]; xq1 = xrow[1]; xq2 = xrow[2]; xq3 = xrow[3]; }

    __syncthreads();

// select x value for compile-time step S (fully unrolled -> constant folded)
#define XV(S)                                                                       \
    ((S) == 0 ? xq0.x : (S) == 1 ? xq0.y : (S) == 2 ? xq0.z : (S) == 3 ? xq0.w      \
   : (S) == 4 ? xq1.x : (S) == 5 ? xq1.y : (S) == 6 ? xq1.z : (S) == 7 ? xq1.w      \
   : (S) == 8 ? xq2.x : (S) == 9 ? xq2.y : (S) == 10 ? xq2.z : (S) == 11 ? xq2.w    \
   : (S) == 12 ? xq3.x : (S) == 13 ? xq3.y : (S) == 14 ? xq3.z : xq3.w)

// 12 packed dots of row triple (V0,V1,V2) vs weight triple (W0,W1,W2)
#define DOT12(V0_, V1_, V2_, W0_, W1_, W2_)                                         \
    a0 = dot2f(V0_.x, W0_.x, a0); a1 = dot2f(V0_.y, W0_.y, a1);                     \
    a2 = dot2f(V0_.z, W0_.z, a2); a3 = dot2f(V0_.w, W0_.w, a3);                     \
    a0 = dot2f(V1_.x, W1_.x, a0); a1 = dot2f(V1_.y, W1_.y, a1);                     \
    a2 = dot2f(V1_.z, W1_.z, a2); a3 = dot2f(V1_.w, W1_.w, a3);                     \
    a0 = dot2f(V2_.x, W2_.x, a0); a1 = dot2f(V2_.y, W2_.y, a1);                     \
    a2 = dot2f(V2_.z, W2_.z, a2); a3 = dot2f(V2_.w, W2_.w, a3);

    // ---- chunked, layer-skewed scan: tick c, layer l handles t in [(c-l)*K, +K) ----
    for (int c = 0; c < CTOT; ++c) {
        const int wp = c & 1, rp = wp ^ 1;
        _Float16* owW = &hbuf[wp][bl][l][0][0];                 // own rows, write parity
        const _Float16* owR0 = &hbuf[rp][bl][l][K - 1][0];      // own row for s=0
        if (c >= l && c < l + NC) {
            if (l == 0) {
                // prefetch next chunk's 16 x values (hidden under this chunk)
                float4 xn0, xn1, xn2, xn3;
                const bool pf = (c + 1 < NC);
                if (pf) {
                    const float4* xn = (const float4*)(x + (size_t)bg * T_LEN
                                                         + (size_t)(c + 1) * K);
                    xn0 = xn[0]; xn1 = xn[1]; xn2 = xn[2]; xn3 = xn[3];
                }
                #pragma unroll
                for (int s = 0; s < K; ++s) {
                    const _Float16* own = (s == 0) ? owR0 : owW + (s - 1) * HID;
                    const int4v o0 = ((const int4v*)own)[0];
                    const int4v o1 = ((const int4v*)own)[1];
                    const int4v o2 = ((const int4v*)own)[2];
                    float a0 = fmaf(wx0, XV(s), bias), a1 = 0.f, a2 = 0.f, a3 = 0.f;
                    DOT12(o0, o1, o2, whA, whB, whC);
                    cur = fmaxf((a0 + a1) + (a2 + a3), 0.f);
                    if (act) owW[s * HID + j] = (_Float16)cur;
                }
                if (pf) { xq0 = xn0; xq1 = xn1; xq2 = xn2; xq3 = xn3; }
            } else {
                const _Float16* inpB = &hbuf[rp][bl][l - 1][0][0];
                int4v iA0 = ((const int4v*)inpB)[0];
                int4v iA1 = ((const int4v*)inpB)[1];
                int4v iA2 = ((const int4v*)inpB)[2];
                #pragma unroll
                for (int s = 0; s < K; ++s) {
                    int4v iB0, iB1, iB2;
                    if (s + 1 < K) {
                        const int4v* nr = (const int4v*)(inpB + (s + 1) * HID);
                        iB0 = nr[0]; iB1 = nr[1]; iB2 = nr[2];
                    }
                    const _Float16* own = (s == 0) ? owR0 : owW + (s - 1) * HID;
                    const int4v o0 = ((const int4v*)own)[0];
                    const int4v o1 = ((const int4v*)own)[1];
                    const int4v o2 = ((const int4v*)own)[2];
                    float a0 = bias, a1 = 0.f, a2 = 0.f, a3 = 0.f;
                    DOT12(iA0, iA1, iA2, wiA, wiB, wiC);
                    DOT12(o0, o1, o2, whA, whB, whC);
                    cur = fmaxf((a0 + a1) + (a2 + a3), 0.f);
                    if (act) owW[s * HID + j] = (_Float16)cur;
                    if (s + 1 < K) { iA0 = iB0; iA1 = iB1; iA2 = iB2; }
                }
            }
        }
        __syncthreads();
    }
#undef DOT12
#undef XV

    // ---- h_final from the f32 running value ----
    if (act) out[BATCH + (l * BATCH + bg) * HID + j] = cur;

    // ---- MLP head on h2(T-1) ----
    if (l == 2 && act) h2f[bl][j] = cur;
    __syncthreads();
    if (l == 2 && act) {
        const float4* w1r = (const float4*)(W1 + j * HID);
        const float4* hv  = (const float4*)&h2f[bl][0];
        float a = b1[j];
        a = dot4(w1r[0], hv[0], a); a = dot4(w1r[1], hv[1], a);
        a = dot4(w1r[2], hv[2], a); a = dot4(w1r[3], hv[3], a);
        a = dot4(w1r[4], hv[4], a); a = dot4(w1r[5], hv[5], a);
        mbuf[bl][j] = fmaxf(a, 0.f);
    }
    __syncthreads();
    if (l == 2 && jj == 0) {
        float a = b2[0];
        #pragma unroll
        for (int k = 0; k < HID; ++k) a = fmaf(W2[k], mbuf[bl][k], a);
        out[bg] = fmaxf(a, 0.f);
    }
}

extern "C" void kernel_launch(void* const* d_in, const int* in_sizes, int n_in,
                              void* d_out, int out_size, void* d_ws, size_t ws_size,
                              hipStream_t stream) {
    const float* x    = (const float*)d_in[0];
    const float* h_in = (const float*)d_in[1];
    const float* Wih0 = (const float*)d_in[2];
    const float* bih0 = (const float*)d_in[3];
    const float* Whh0 = (const float*)d_in[4];
    const float* bhh0 = (const float*)d_in[5];
    const float* Wih1 = (const float*)d_in[6];
    const float* bih1 = (const float*)d_in[7];
    const float* Whh1 = (const float*)d_in[8];
    const float* bhh1 = (const float*)d_in[9];
    const float* Wih2 = (const float*)d_in[10];
    const float* bih2 = (const float*)d_in[11];
    const float* Whh2 = (const float*)d_in[12];
    const float* bhh2 = (const float*)d_in[13];
    const float* W1   = (const float*)d_in[14];
    const float* b1   = (const float*)d_in[15];
    const float* W2   = (const float*)d_in[16];
    const float* b2   = (const float*)d_in[17];
    float* out = (float*)d_out;

    dim3 grid(BATCH / NB);   // 512 blocks -> 2 blocks/CU
    dim3 block(TPB);         // 3 full waves (wave == layer)
    hipLaunchKernelGGL(rnn_scan_kernel, grid, block, 0, stream,
                       x, h_in, Wih0, bih0, Whh0, bhh0,
                       Wih1, bih1, Whh1, bhh1, Wih2, bih2, Whh2, bhh2,
                       W1, b1, W2, b2, out);
}